// Round 3
// baseline (109.818 us; speedup 1.0000x reference)
//
#include <hip/hip_runtime.h>
#include <math.h>

namespace {

constexpr int Bsz = 64;
constexpr int Nn  = 1024;
constexpr int Dd  = 512;
constexpr int NCH = 32;            // n-chunks for column-sum pass
constexpr int RPC = Nn / NCH;      // 32 rows per chunk
constexpr int SCH = 16;            // n-chunks for fused pass
constexpr int SRW = Nn / SCH;      // 64 rows per fused block
constexpr float SCALE = 0.044194173824159216f;  // 1/sqrt(512)

// Pass 1: partial column sums of x. grid(B, NCH), block 128.
__global__ __launch_bounds__(128) void k_colsum(const float* __restrict__ x,
                                                float* __restrict__ part) {
  const int b = blockIdx.x, ch = blockIdx.y, t = threadIdx.x;
  const float* base = x + ((size_t)b * Nn + (size_t)ch * RPC) * Dd;
  float4 acc = make_float4(0.f, 0.f, 0.f, 0.f);
  #pragma unroll 8
  for (int n = 0; n < RPC; ++n) {
    float4 v = *reinterpret_cast<const float4*>(base + (size_t)n * Dd + t * 4);
    acc.x += v.x; acc.y += v.y; acc.z += v.z; acc.w += v.w;
  }
  *reinterpret_cast<float4*>(part + (size_t)(b * NCH + ch) * Dd + t * 4) = acc;
}

// Pass 2: xbar -> kbar = xbar@Wk^T + bk -> u = kbar@Wq. grid(B), 512 thr (8 waves).
// (c = bq.kbar dropped: softmax is shift-invariant.)
__global__ __launch_bounds__(512) void k_prep(const float* __restrict__ part,
                                              const float* __restrict__ Wq,
                                              const float* __restrict__ Wk,
                                              const float* __restrict__ bk,
                                              float* __restrict__ u) {
  const int b = blockIdx.x, t = threadIdx.x, wave = t >> 6, lane = t & 63;
  __shared__ __align__(16) float xbar[Dd];
  __shared__ float kbar[Dd];

  float acc = 0.f;
  for (int ch = 0; ch < NCH; ++ch) acc += part[(size_t)(b * NCH + ch) * Dd + t];
  xbar[t] = acc * (1.0f / Nn);
  __syncthreads();

  const float4 xv1 = *reinterpret_cast<const float4*>(xbar + lane * 4);
  const float4 xv2 = *reinterpret_cast<const float4*>(xbar + 256 + lane * 4);
  // wave-per-row (coalesced), 64 rows per wave, 2 rows in flight
  for (int i = 0; i < 64; i += 2) {
    const int e0 = wave * 64 + i, e1 = e0 + 1;
    const float4* r0 = reinterpret_cast<const float4*>(Wk + (size_t)e0 * Dd);
    const float4* r1 = reinterpret_cast<const float4*>(Wk + (size_t)e1 * Dd);
    const float4 a0 = r0[lane], b0 = r0[64 + lane];
    const float4 a1 = r1[lane], b1 = r1[64 + lane];
    float d0 = a0.x*xv1.x + a0.y*xv1.y + a0.z*xv1.z + a0.w*xv1.w
             + b0.x*xv2.x + b0.y*xv2.y + b0.z*xv2.z + b0.w*xv2.w;
    float d1 = a1.x*xv1.x + a1.y*xv1.y + a1.z*xv1.z + a1.w*xv1.w
             + b1.x*xv2.x + b1.y*xv2.y + b1.z*xv2.z + b1.w*xv2.w;
    #pragma unroll
    for (int off = 32; off > 0; off >>= 1) {
      d0 += __shfl_xor(d0, off);
      d1 += __shfl_xor(d1, off);
    }
    if (lane == 0) { kbar[e0] = bk[e0] + d0; kbar[e1] = bk[e1] + d1; }
  }
  __syncthreads();

  // u[t] = sum_e kbar[e] * Wq[e][t]  (coalesced column access)
  float uu = 0.f;
  #pragma unroll 4
  for (int e = 0; e < Dd; ++e) uu += kbar[e] * Wq[(size_t)e * Dd + t];
  u[(size_t)b * Dd + t] = uu;
}

// Pass 3 (fused, branch-free): s[b,n] = x_n.u_b * SCALE; accumulate exp(s_n)*x_n
// (no max subtraction -- |s| << 1 by construction; finalize rescales exactly).
// grid(B, SCH), block 256 (4 waves, 16 rows each, 2 rows in flight).
__global__ __launch_bounds__(256) void k_fused(const float* __restrict__ x,
                                               const float* __restrict__ u,
                                               float* __restrict__ s,
                                               float* __restrict__ P) {
  const int b = blockIdx.x, ch = blockIdx.y, t = threadIdx.x;
  const int wave = t >> 6, lane = t & 63;
  const float4 u1 = *reinterpret_cast<const float4*>(u + (size_t)b * Dd + lane * 4);
  const float4 u2 = *reinterpret_cast<const float4*>(u + (size_t)b * Dd + 256 + lane * 4);
  const float* xb = x + ((size_t)b * Nn + (size_t)ch * SRW) * Dd;
  float* sb = s + (size_t)b * Nn + (size_t)ch * SRW;

  float4 a1 = make_float4(0.f, 0.f, 0.f, 0.f);
  float4 a2 = make_float4(0.f, 0.f, 0.f, 0.f);

  #pragma unroll 2
  for (int i = 0; i < 16; i += 2) {
    const int r0 = wave + 4 * i, r1 = wave + 4 * (i + 1);
    const float4* xr0 = reinterpret_cast<const float4*>(xb + (size_t)r0 * Dd);
    const float4* xr1 = reinterpret_cast<const float4*>(xb + (size_t)r1 * Dd);
    const float4 va0 = xr0[lane], vb0 = xr0[64 + lane];
    const float4 va1 = xr1[lane], vb1 = xr1[64 + lane];
    float d0 = va0.x*u1.x + va0.y*u1.y + va0.z*u1.z + va0.w*u1.w
             + vb0.x*u2.x + vb0.y*u2.y + vb0.z*u2.z + vb0.w*u2.w;
    float d1 = va1.x*u1.x + va1.y*u1.y + va1.z*u1.z + va1.w*u1.w
             + vb1.x*u2.x + vb1.y*u2.y + vb1.z*u2.z + vb1.w*u2.w;
    #pragma unroll
    for (int off = 32; off > 0; off >>= 1) {
      d0 += __shfl_xor(d0, off);
      d1 += __shfl_xor(d1, off);
    }
    const float s0 = d0 * SCALE, s1 = d1 * SCALE;
    if (lane == 0) { sb[r0] = s0; sb[r1] = s1; }
    const float e0 = __expf(s0), e1 = __expf(s1);
    a1.x += e0*va0.x + e1*va1.x; a1.y += e0*va0.y + e1*va1.y;
    a1.z += e0*va0.z + e1*va1.z; a1.w += e0*va0.w + e1*va1.w;
    a2.x += e0*vb0.x + e1*vb1.x; a2.y += e0*vb0.y + e1*vb1.y;
    a2.z += e0*vb0.z + e1*vb1.z; a2.w += e0*vb0.w + e1*vb1.w;
  }

  // parallel 4-section wave combine in LDS
  __shared__ __align__(16) float pacc[4][Dd];
  *reinterpret_cast<float4*>(&pacc[wave][lane * 4]) = a1;
  *reinterpret_cast<float4*>(&pacc[wave][256 + lane * 4]) = a2;
  __syncthreads();
  float* Pb = P + (size_t)(b * SCH + ch) * Dd;
  Pb[t]       = pacc[0][t]       + pacc[1][t]       + pacc[2][t]       + pacc[3][t];
  Pb[t + 256] = pacc[0][t + 256] + pacc[1][t + 256] + pacc[2][t + 256] + pacc[3][t + 256];
}

// Pass 4: exact softmax over s -> w; agg = (sum_ch P_ch) * exp(-m)/Z. grid(B), 256 thr.
__global__ __launch_bounds__(256) void k_final(const float* __restrict__ s,
                                               const float* __restrict__ P,
                                               float* __restrict__ w,
                                               float* __restrict__ agg) {
  const int b = blockIdx.x, t = threadIdx.x;
  const int wave = t >> 6, lane = t & 63;
  __shared__ float lred[4];

  float v[4];
  for (int i = 0; i < 4; ++i) v[i] = s[(size_t)b * Nn + t + i * 256];
  float m = fmaxf(fmaxf(v[0], v[1]), fmaxf(v[2], v[3]));
  #pragma unroll
  for (int off = 32; off > 0; off >>= 1) m = fmaxf(m, __shfl_xor(m, off));
  if (lane == 0) lred[wave] = m;
  __syncthreads();
  m = fmaxf(fmaxf(lred[0], lred[1]), fmaxf(lred[2], lred[3]));
  __syncthreads();

  float e[4];
  float sum = 0.f;
  for (int i = 0; i < 4; ++i) { e[i] = expf(v[i] - m); sum += e[i]; }
  #pragma unroll
  for (int off = 32; off > 0; off >>= 1) sum += __shfl_xor(sum, off);
  if (lane == 0) lred[wave] = sum;
  __syncthreads();
  sum = lred[0] + lred[1] + lred[2] + lred[3];
  const float inv = 1.0f / sum;
  for (int i = 0; i < 4; ++i) w[(size_t)b * Nn + t + i * 256] = e[i] * inv;

  const float coef = expf(-m) * inv;   // P used exp(s) unshifted
  for (int d = t; d < Dd; d += 256) {
    float acc = 0.f;
    for (int chh = 0; chh < SCH; ++chh)
      acc += P[(size_t)(b * SCH + chh) * Dd + d];
    agg[(size_t)b * Dd + d] = acc * coef;
  }
}

}  // namespace

extern "C" void kernel_launch(void* const* d_in, const int* in_sizes, int n_in,
                              void* d_out, int out_size, void* d_ws, size_t ws_size,
                              hipStream_t stream) {
  const float* x  = (const float*)d_in[0];
  const float* Wq = (const float*)d_in[1];
  const float* Wk = (const float*)d_in[3];
  const float* bk = (const float*)d_in[4];

  float* out = (float*)d_out;
  float* agg = out;                       // [B][D]
  float* w   = out + (size_t)Bsz * Dd;    // [B][N]

  // workspace (floats): part | u | s | P   (~6.4 MiB)
  float* part = (float*)d_ws;                         // B*NCH*D
  float* u    = part + (size_t)Bsz * NCH * Dd;        // B*D
  float* s    = u + (size_t)Bsz * Dd;                 // B*N
  float* P    = s + (size_t)Bsz * Nn;                 // B*SCH*D

  k_colsum<<<dim3(Bsz, NCH), 128, 0, stream>>>(x, part);
  k_prep  <<<Bsz, 512, 0, stream>>>(part, Wq, Wk, bk, u);
  k_fused <<<dim3(Bsz, SCH), 256, 0, stream>>>(x, u, s, P);
  k_final <<<Bsz, 256, 0, stream>>>(s, P, w, agg);
}

// Round 4
// 63.992 us; speedup vs baseline: 1.7161x; 1.7161x over previous
//
#include <hip/hip_runtime.h>
#include <math.h>

namespace {

constexpr int Bsz = 64;
constexpr int Nn  = 1024;
constexpr int Dd  = 512;
constexpr int NCH = 32;            // n-chunks for column-sum pass
constexpr int RPC = Nn / NCH;      // 32 rows per chunk
constexpr int SCH = 16;            // n-chunks for fused pass
constexpr int SRW = Nn / SCH;      // 64 rows per fused block
constexpr int UCH = 4;             // e-chunks for u matvec
constexpr float SCALE = 0.044194173824159216f;  // 1/sqrt(512)

// Pass 1: partial column sums of x. grid(B, NCH), block 128. HBM-bound.
__global__ __launch_bounds__(128) void k_colsum(const float* __restrict__ x,
                                                float* __restrict__ part) {
  const int b = blockIdx.x, ch = blockIdx.y, t = threadIdx.x;
  const float* base = x + ((size_t)b * Nn + (size_t)ch * RPC) * Dd;
  float4 acc = make_float4(0.f, 0.f, 0.f, 0.f);
  #pragma unroll 8
  for (int n = 0; n < RPC; ++n) {
    float4 v = *reinterpret_cast<const float4*>(base + (size_t)n * Dd + t * 4);
    acc.x += v.x; acc.y += v.y; acc.z += v.z; acc.w += v.w;
  }
  *reinterpret_cast<float4*>(part + (size_t)(b * NCH + ch) * Dd + t * 4) = acc;
}

// Pass 2: kbar[b][e] = bk[e] + xbar[b] . Wk_row[e].  grid(B, 8), block 256 (4 waves).
// Each block redundantly reduces part[b] -> xbar (64KB from L2), then wave-per-row
// dots for its 64 rows, 2 rows in flight. (c = bq.kbar dropped: softmax shift-inv.)
__global__ __launch_bounds__(256) void k_kbar(const float* __restrict__ part,
                                              const float* __restrict__ Wk,
                                              const float* __restrict__ bk,
                                              float* __restrict__ kbar) {
  const int b = blockIdx.x, g = blockIdx.y, t = threadIdx.x;
  const int wave = t >> 6, lane = t & 63;
  __shared__ __align__(16) float xbar[Dd];

  {
    float acc0 = 0.f, acc1 = 0.f;
    const float* pb = part + (size_t)b * NCH * Dd;
    #pragma unroll 8
    for (int ch = 0; ch < NCH; ++ch) {
      acc0 += pb[(size_t)ch * Dd + t];
      acc1 += pb[(size_t)ch * Dd + t + 256];
    }
    xbar[t]       = acc0 * (1.0f / Nn);
    xbar[t + 256] = acc1 * (1.0f / Nn);
  }
  __syncthreads();

  const float4 xv1 = *reinterpret_cast<const float4*>(xbar + lane * 4);
  const float4 xv2 = *reinterpret_cast<const float4*>(xbar + 256 + lane * 4);

  // wave handles rows [g*64 + wave*16, +16), 2 in flight
  for (int i = 0; i < 16; i += 2) {
    const int e0 = g * 64 + wave * 16 + i, e1 = e0 + 1;
    const float4* r0 = reinterpret_cast<const float4*>(Wk + (size_t)e0 * Dd);
    const float4* r1 = reinterpret_cast<const float4*>(Wk + (size_t)e1 * Dd);
    const float4 a0 = r0[lane], b0 = r0[64 + lane];
    const float4 a1 = r1[lane], b1 = r1[64 + lane];
    float d0 = a0.x*xv1.x + a0.y*xv1.y + a0.z*xv1.z + a0.w*xv1.w
             + b0.x*xv2.x + b0.y*xv2.y + b0.z*xv2.z + b0.w*xv2.w;
    float d1 = a1.x*xv1.x + a1.y*xv1.y + a1.z*xv1.z + a1.w*xv1.w
             + b1.x*xv2.x + b1.y*xv2.y + b1.z*xv2.z + b1.w*xv2.w;
    #pragma unroll
    for (int off = 32; off > 0; off >>= 1) {
      d0 += __shfl_xor(d0, off);
      d1 += __shfl_xor(d1, off);
    }
    if (lane == 0) {
      kbar[(size_t)b * Dd + e0] = bk[e0] + d0;
      kbar[(size_t)b * Dd + e1] = bk[e1] + d1;
    }
  }
}

// Pass 3: upart[b][h][t] = sum_{e in chunk h} kbar[b][e] * Wq[e][t].
// grid(B, UCH), block 512. 4 independent accumulators; kbar chunk in LDS.
__global__ __launch_bounds__(512) void k_u(const float* __restrict__ kbar,
                                           const float* __restrict__ Wq,
                                           float* __restrict__ upart) {
  const int b = blockIdx.x, h = blockIdx.y, t = threadIdx.x;
  constexpr int EC = Dd / UCH;  // 128
  __shared__ float kb[EC];
  if (t < EC) kb[t] = kbar[(size_t)b * Dd + h * EC + t];
  __syncthreads();

  const float* Wbase = Wq + (size_t)(h * EC) * Dd + t;
  float a0 = 0.f, a1 = 0.f, a2 = 0.f, a3 = 0.f;
  #pragma unroll 8
  for (int j = 0; j < EC; j += 4) {
    a0 += kb[j]     * Wbase[(size_t)(j)     * Dd];
    a1 += kb[j + 1] * Wbase[(size_t)(j + 1) * Dd];
    a2 += kb[j + 2] * Wbase[(size_t)(j + 2) * Dd];
    a3 += kb[j + 3] * Wbase[(size_t)(j + 3) * Dd];
  }
  upart[(size_t)(b * UCH + h) * Dd + t] = (a0 + a1) + (a2 + a3);
}

// Pass 4 (fused, branch-free): s[b,n] = x_n.u_b * SCALE; accumulate exp(s_n)*x_n.
// grid(B, SCH), block 256 (4 waves, 16 rows each, 2 rows in flight).
__global__ __launch_bounds__(256) void k_fused(const float* __restrict__ x,
                                               const float* __restrict__ upart,
                                               float* __restrict__ s,
                                               float* __restrict__ P) {
  const int b = blockIdx.x, ch = blockIdx.y, t = threadIdx.x;
  const int wave = t >> 6, lane = t & 63;

  // u = sum of 4 partials (tiny L2 reads)
  float4 u1 = make_float4(0.f, 0.f, 0.f, 0.f);
  float4 u2 = make_float4(0.f, 0.f, 0.f, 0.f);
  #pragma unroll
  for (int h = 0; h < UCH; ++h) {
    const float* ub = upart + (size_t)(b * UCH + h) * Dd;
    const float4 p1 = *reinterpret_cast<const float4*>(ub + lane * 4);
    const float4 p2 = *reinterpret_cast<const float4*>(ub + 256 + lane * 4);
    u1.x += p1.x; u1.y += p1.y; u1.z += p1.z; u1.w += p1.w;
    u2.x += p2.x; u2.y += p2.y; u2.z += p2.z; u2.w += p2.w;
  }

  const float* xb = x + ((size_t)b * Nn + (size_t)ch * SRW) * Dd;
  float* sb = s + (size_t)b * Nn + (size_t)ch * SRW;

  float4 a1 = make_float4(0.f, 0.f, 0.f, 0.f);
  float4 a2 = make_float4(0.f, 0.f, 0.f, 0.f);

  #pragma unroll 2
  for (int i = 0; i < 16; i += 2) {
    const int r0 = wave + 4 * i, r1 = wave + 4 * (i + 1);
    const float4* xr0 = reinterpret_cast<const float4*>(xb + (size_t)r0 * Dd);
    const float4* xr1 = reinterpret_cast<const float4*>(xb + (size_t)r1 * Dd);
    const float4 va0 = xr0[lane], vb0 = xr0[64 + lane];
    const float4 va1 = xr1[lane], vb1 = xr1[64 + lane];
    float d0 = va0.x*u1.x + va0.y*u1.y + va0.z*u1.z + va0.w*u1.w
             + vb0.x*u2.x + vb0.y*u2.y + vb0.z*u2.z + vb0.w*u2.w;
    float d1 = va1.x*u1.x + va1.y*u1.y + va1.z*u1.z + va1.w*u1.w
             + vb1.x*u2.x + vb1.y*u2.y + vb1.z*u2.z + vb1.w*u2.w;
    #pragma unroll
    for (int off = 32; off > 0; off >>= 1) {
      d0 += __shfl_xor(d0, off);
      d1 += __shfl_xor(d1, off);
    }
    const float s0 = d0 * SCALE, s1 = d1 * SCALE;
    if (lane == 0) { sb[r0] = s0; sb[r1] = s1; }
    const float e0 = __expf(s0), e1 = __expf(s1);
    a1.x += e0*va0.x + e1*va1.x; a1.y += e0*va0.y + e1*va1.y;
    a1.z += e0*va0.z + e1*va1.z; a1.w += e0*va0.w + e1*va1.w;
    a2.x += e0*vb0.x + e1*vb1.x; a2.y += e0*vb0.y + e1*vb1.y;
    a2.z += e0*vb0.z + e1*vb1.z; a2.w += e0*vb0.w + e1*vb1.w;
  }

  __shared__ __align__(16) float pacc[4][Dd];
  *reinterpret_cast<float4*>(&pacc[wave][lane * 4]) = a1;
  *reinterpret_cast<float4*>(&pacc[wave][256 + lane * 4]) = a2;
  __syncthreads();
  float* Pb = P + (size_t)(b * SCH + ch) * Dd;
  Pb[t]       = pacc[0][t]       + pacc[1][t]       + pacc[2][t]       + pacc[3][t];
  Pb[t + 256] = pacc[0][t + 256] + pacc[1][t + 256] + pacc[2][t + 256] + pacc[3][t + 256];
}

// Pass 5: exact softmax over s -> w; agg = (sum_ch P_ch) * exp(-m)/Z. grid(B), 256 thr.
__global__ __launch_bounds__(256) void k_final(const float* __restrict__ s,
                                               const float* __restrict__ P,
                                               float* __restrict__ w,
                                               float* __restrict__ agg) {
  const int b = blockIdx.x, t = threadIdx.x;
  const int wave = t >> 6, lane = t & 63;
  __shared__ float lred[4];

  float v[4];
  for (int i = 0; i < 4; ++i) v[i] = s[(size_t)b * Nn + t + i * 256];
  float m = fmaxf(fmaxf(v[0], v[1]), fmaxf(v[2], v[3]));
  #pragma unroll
  for (int off = 32; off > 0; off >>= 1) m = fmaxf(m, __shfl_xor(m, off));
  if (lane == 0) lred[wave] = m;
  __syncthreads();
  m = fmaxf(fmaxf(lred[0], lred[1]), fmaxf(lred[2], lred[3]));
  __syncthreads();

  float e[4];
  float sum = 0.f;
  for (int i = 0; i < 4; ++i) { e[i] = expf(v[i] - m); sum += e[i]; }
  #pragma unroll
  for (int off = 32; off > 0; off >>= 1) sum += __shfl_xor(sum, off);
  if (lane == 0) lred[wave] = sum;
  __syncthreads();
  sum = lred[0] + lred[1] + lred[2] + lred[3];
  const float inv = 1.0f / sum;
  for (int i = 0; i < 4; ++i) w[(size_t)b * Nn + t + i * 256] = e[i] * inv;

  const float coef = expf(-m) * inv;   // P used exp(s) unshifted
  for (int d = t; d < Dd; d += 256) {
    float acc = 0.f;
    for (int chh = 0; chh < SCH; ++chh)
      acc += P[(size_t)(b * SCH + chh) * Dd + d];
    agg[(size_t)b * Dd + d] = acc * coef;
  }
}

}  // namespace

extern "C" void kernel_launch(void* const* d_in, const int* in_sizes, int n_in,
                              void* d_out, int out_size, void* d_ws, size_t ws_size,
                              hipStream_t stream) {
  const float* x  = (const float*)d_in[0];
  const float* Wq = (const float*)d_in[1];
  const float* Wk = (const float*)d_in[3];
  const float* bk = (const float*)d_in[4];

  float* out = (float*)d_out;
  float* agg = out;                       // [B][D]
  float* w   = out + (size_t)Bsz * Dd;    // [B][N]

  // workspace (floats): part | kbar | upart | s | P   (~7.0 MiB)
  float* part  = (float*)d_ws;                          // B*NCH*D
  float* kbar  = part + (size_t)Bsz * NCH * Dd;         // B*D
  float* upart = kbar + (size_t)Bsz * Dd;               // B*UCH*D
  float* s     = upart + (size_t)Bsz * UCH * Dd;        // B*N
  float* P     = s + (size_t)Bsz * Nn;                  // B*SCH*D

  k_colsum<<<dim3(Bsz, NCH), 128, 0, stream>>>(x, part);
  k_kbar  <<<dim3(Bsz, 8), 256, 0, stream>>>(part, Wk, bk, kbar);
  k_u     <<<dim3(Bsz, UCH), 512, 0, stream>>>(kbar, Wq, upart);
  k_fused <<<dim3(Bsz, SCH), 256, 0, stream>>>(x, upart, s, P);
  k_final <<<Bsz, 256, 0, stream>>>(s, P, w, agg);
}

// Round 5
// 63.772 us; speedup vs baseline: 1.7220x; 1.0034x over previous
//
#include <hip/hip_runtime.h>
#include <math.h>

namespace {

constexpr int Bsz = 64;
constexpr int Nn  = 1024;
constexpr int Dd  = 512;
constexpr int NCH = 32;            // n-chunks for column-sum pass
constexpr int RPC = Nn / NCH;      // 32 rows per chunk
constexpr int SCH = 32;            // n-chunks for fused pass
constexpr int SRW = Nn / SCH;      // 32 rows per fused block
constexpr int GCH = 8;             // e-slices for prep (64 rows each)
constexpr float SCALE = 0.044194173824159216f;  // 1/sqrt(512)

// Pass 1: partial column sums of x. grid(B, NCH), block 128. HBM-bound.
__global__ __launch_bounds__(128) void k_colsum(const float* __restrict__ x,
                                                float* __restrict__ part) {
  const int b = blockIdx.x, ch = blockIdx.y, t = threadIdx.x;
  const float* base = x + ((size_t)b * Nn + (size_t)ch * RPC) * Dd;
  float4 acc = make_float4(0.f, 0.f, 0.f, 0.f);
  #pragma unroll 8
  for (int n = 0; n < RPC; ++n) {
    float4 v = *reinterpret_cast<const float4*>(base + (size_t)n * Dd + t * 4);
    acc.x += v.x; acc.y += v.y; acc.z += v.z; acc.w += v.w;
  }
  *reinterpret_cast<float4*>(part + (size_t)(b * NCH + ch) * Dd + t * 4) = acc;
}

// Pass 2 (merged prep): block (b,g) reduces part->xbar (redundant, L2), computes
// kbar slice [g*64, g*64+64) via wave-per-row dots, then emits this slice's
// partial of u: upart[b][g][d] = sum_{e in slice} kbar_e * Wq[e][d].
// grid(B, GCH), block 256 (4 waves). (c = bq.kbar dropped: softmax shift-inv.)
__global__ __launch_bounds__(256) void k_prep2(const float* __restrict__ part,
                                               const float* __restrict__ Wq,
                                               const float* __restrict__ Wk,
                                               const float* __restrict__ bk,
                                               float* __restrict__ upart) {
  const int b = blockIdx.x, g = blockIdx.y, t = threadIdx.x;
  const int wave = t >> 6, lane = t & 63;
  __shared__ __align__(16) float xbar[Dd];
  __shared__ float kb[64];

  {
    float acc0 = 0.f, acc1 = 0.f;
    const float* pb = part + (size_t)b * NCH * Dd;
    #pragma unroll 8
    for (int ch = 0; ch < NCH; ++ch) {
      acc0 += pb[(size_t)ch * Dd + t];
      acc1 += pb[(size_t)ch * Dd + t + 256];
    }
    xbar[t]       = acc0 * (1.0f / Nn);
    xbar[t + 256] = acc1 * (1.0f / Nn);
  }
  __syncthreads();

  const float4 xv1 = *reinterpret_cast<const float4*>(xbar + lane * 4);
  const float4 xv2 = *reinterpret_cast<const float4*>(xbar + 256 + lane * 4);

  // wave handles slice rows [wave*16, wave*16+16), 2 in flight
  for (int i = 0; i < 16; i += 2) {
    const int l0 = wave * 16 + i, l1 = l0 + 1;
    const int e0 = g * 64 + l0, e1 = e0 + 1;
    const float4* r0 = reinterpret_cast<const float4*>(Wk + (size_t)e0 * Dd);
    const float4* r1 = reinterpret_cast<const float4*>(Wk + (size_t)e1 * Dd);
    const float4 a0 = r0[lane], b0 = r0[64 + lane];
    const float4 a1 = r1[lane], b1 = r1[64 + lane];
    float d0 = a0.x*xv1.x + a0.y*xv1.y + a0.z*xv1.z + a0.w*xv1.w
             + b0.x*xv2.x + b0.y*xv2.y + b0.z*xv2.z + b0.w*xv2.w;
    float d1 = a1.x*xv1.x + a1.y*xv1.y + a1.z*xv1.z + a1.w*xv1.w
             + b1.x*xv2.x + b1.y*xv2.y + b1.z*xv2.z + b1.w*xv2.w;
    #pragma unroll
    for (int off = 32; off > 0; off >>= 1) {
      d0 += __shfl_xor(d0, off);
      d1 += __shfl_xor(d1, off);
    }
    if (lane == 0) { kb[l0] = bk[e0] + d0; kb[l1] = bk[e1] + d1; }
  }
  __syncthreads();

  // u-partial for this slice: thread t covers d = t and d = t+256.
  const float* Wbase = Wq + (size_t)(g * 64) * Dd;
  float a0 = 0.f, a1 = 0.f, a2 = 0.f, a3 = 0.f;
  #pragma unroll 8
  for (int e = 0; e < 64; e += 2) {
    const float k0 = kb[e], k1 = kb[e + 1];
    a0 += k0 * Wbase[(size_t)e * Dd + t];
    a1 += k0 * Wbase[(size_t)e * Dd + t + 256];
    a2 += k1 * Wbase[(size_t)(e + 1) * Dd + t];
    a3 += k1 * Wbase[(size_t)(e + 1) * Dd + t + 256];
  }
  float* ub = upart + (size_t)(b * GCH + g) * Dd;
  ub[t]       = a0 + a2;
  ub[t + 256] = a1 + a3;
}

// Pass 3 (fused, branch-free): s[b,n] = x_n.u_b * SCALE; accumulate exp(s_n)*x_n.
// grid(B, SCH), block 256 (4 waves, 8 rows each, 2 in flight).
__global__ __launch_bounds__(256) void k_fused(const float* __restrict__ x,
                                               const float* __restrict__ upart,
                                               float* __restrict__ s,
                                               float* __restrict__ P) {
  const int b = blockIdx.x, ch = blockIdx.y, t = threadIdx.x;
  const int wave = t >> 6, lane = t & 63;

  // u = sum of GCH partials (tiny L2 reads)
  float4 u1 = make_float4(0.f, 0.f, 0.f, 0.f);
  float4 u2 = make_float4(0.f, 0.f, 0.f, 0.f);
  #pragma unroll
  for (int h = 0; h < GCH; ++h) {
    const float* ub = upart + (size_t)(b * GCH + h) * Dd;
    const float4 p1 = *reinterpret_cast<const float4*>(ub + lane * 4);
    const float4 p2 = *reinterpret_cast<const float4*>(ub + 256 + lane * 4);
    u1.x += p1.x; u1.y += p1.y; u1.z += p1.z; u1.w += p1.w;
    u2.x += p2.x; u2.y += p2.y; u2.z += p2.z; u2.w += p2.w;
  }

  const float* xb = x + ((size_t)b * Nn + (size_t)ch * SRW) * Dd;
  float* sb = s + (size_t)b * Nn + (size_t)ch * SRW;

  float4 a1 = make_float4(0.f, 0.f, 0.f, 0.f);
  float4 a2 = make_float4(0.f, 0.f, 0.f, 0.f);

  #pragma unroll 2
  for (int i = 0; i < 8; i += 2) {
    const int r0 = wave + 4 * i, r1 = wave + 4 * (i + 1);
    const float4* xr0 = reinterpret_cast<const float4*>(xb + (size_t)r0 * Dd);
    const float4* xr1 = reinterpret_cast<const float4*>(xb + (size_t)r1 * Dd);
    const float4 va0 = xr0[lane], vb0 = xr0[64 + lane];
    const float4 va1 = xr1[lane], vb1 = xr1[64 + lane];
    float d0 = va0.x*u1.x + va0.y*u1.y + va0.z*u1.z + va0.w*u1.w
             + vb0.x*u2.x + vb0.y*u2.y + vb0.z*u2.z + vb0.w*u2.w;
    float d1 = va1.x*u1.x + va1.y*u1.y + va1.z*u1.z + va1.w*u1.w
             + vb1.x*u2.x + vb1.y*u2.y + vb1.z*u2.z + vb1.w*u2.w;
    #pragma unroll
    for (int off = 32; off > 0; off >>= 1) {
      d0 += __shfl_xor(d0, off);
      d1 += __shfl_xor(d1, off);
    }
    const float s0 = d0 * SCALE, s1 = d1 * SCALE;
    if (lane == 0) { sb[r0] = s0; sb[r1] = s1; }
    const float e0 = __expf(s0), e1 = __expf(s1);
    a1.x += e0*va0.x + e1*va1.x; a1.y += e0*va0.y + e1*va1.y;
    a1.z += e0*va0.z + e1*va1.z; a1.w += e0*va0.w + e1*va1.w;
    a2.x += e0*vb0.x + e1*vb1.x; a2.y += e0*vb0.y + e1*vb1.y;
    a2.z += e0*vb0.z + e1*vb1.z; a2.w += e0*vb0.w + e1*vb1.w;
  }

  __shared__ __align__(16) float pacc[4][Dd];
  *reinterpret_cast<float4*>(&pacc[wave][lane * 4]) = a1;
  *reinterpret_cast<float4*>(&pacc[wave][256 + lane * 4]) = a2;
  __syncthreads();
  float* Pb = P + (size_t)(b * SCH + ch) * Dd;
  Pb[t]       = pacc[0][t]       + pacc[1][t]       + pacc[2][t]       + pacc[3][t];
  Pb[t + 256] = pacc[0][t + 256] + pacc[1][t + 256] + pacc[2][t + 256] + pacc[3][t + 256];
}

// Pass 4: exact softmax over s -> w; agg = (sum_ch P_ch) * exp(-m)/Z. grid(B), 256 thr.
__global__ __launch_bounds__(256) void k_final(const float* __restrict__ s,
                                               const float* __restrict__ P,
                                               float* __restrict__ w,
                                               float* __restrict__ agg) {
  const int b = blockIdx.x, t = threadIdx.x;
  const int wave = t >> 6, lane = t & 63;
  __shared__ float lred[4];

  float v[4];
  for (int i = 0; i < 4; ++i) v[i] = s[(size_t)b * Nn + t + i * 256];
  float m = fmaxf(fmaxf(v[0], v[1]), fmaxf(v[2], v[3]));
  #pragma unroll
  for (int off = 32; off > 0; off >>= 1) m = fmaxf(m, __shfl_xor(m, off));
  if (lane == 0) lred[wave] = m;
  __syncthreads();
  m = fmaxf(fmaxf(lred[0], lred[1]), fmaxf(lred[2], lred[3]));
  __syncthreads();

  float e[4];
  float sum = 0.f;
  for (int i = 0; i < 4; ++i) { e[i] = expf(v[i] - m); sum += e[i]; }
  #pragma unroll
  for (int off = 32; off > 0; off >>= 1) sum += __shfl_xor(sum, off);
  if (lane == 0) lred[wave] = sum;
  __syncthreads();
  sum = lred[0] + lred[1] + lred[2] + lred[3];
  const float inv = 1.0f / sum;
  for (int i = 0; i < 4; ++i) w[(size_t)b * Nn + t + i * 256] = e[i] * inv;

  const float coef = expf(-m) * inv;   // P used exp(s) unshifted
  for (int d = t; d < Dd; d += 256) {
    float acc = 0.f;
    for (int chh = 0; chh < SCH; ++chh)
      acc += P[(size_t)(b * SCH + chh) * Dd + d];
    agg[(size_t)b * Dd + d] = acc * coef;
  }
}

}  // namespace

extern "C" void kernel_launch(void* const* d_in, const int* in_sizes, int n_in,
                              void* d_out, int out_size, void* d_ws, size_t ws_size,
                              hipStream_t stream) {
  const float* x  = (const float*)d_in[0];
  const float* Wq = (const float*)d_in[1];
  const float* Wk = (const float*)d_in[3];
  const float* bk = (const float*)d_in[4];

  float* out = (float*)d_out;
  float* agg = out;                       // [B][D]
  float* w   = out + (size_t)Bsz * Dd;    // [B][N]

  // workspace (floats): part | upart | s | P   (~9.5 MiB)
  float* part  = (float*)d_ws;                          // B*NCH*D
  float* upart = part + (size_t)Bsz * NCH * Dd;         // B*GCH*D
  float* s     = upart + (size_t)Bsz * GCH * Dd;        // B*N
  float* P     = s + (size_t)Bsz * Nn;                  // B*SCH*D

  k_colsum<<<dim3(Bsz, NCH), 128, 0, stream>>>(x, part);
  k_prep2 <<<dim3(Bsz, GCH), 256, 0, stream>>>(part, Wq, Wk, bk, upart);
  k_fused <<<dim3(Bsz, SCH), 256, 0, stream>>>(x, upart, s, P);
  k_final <<<Bsz, 256, 0, stream>>>(s, P, w, agg);
}